// Round 1
// baseline (31.821 us; speedup 1.0000x reference)
//
#include <hip/hip_runtime.h>
#include <cmath>

#define BB 64
#define TT 2048
#define DD 512
#define EE 1024
#define HH 102
#define COEF 0.3989422917366028f

__device__ __forceinline__ float sigmoidf_(float x) { return 1.0f / (1.0f + expf(-x)); }

// Kernel A: per-batch MLP -> sig, mu -> windowed normalized alpha into ws meta.
// meta layout per b (stride 64 floats): [0]=j0, [1]=n, [2..63]=alpha (zero-padded)
__global__ __launch_bounds__(256) void k_alpha(const float* __restrict__ query,
                                               const float* __restrict__ mu_tm1,
                                               const float* __restrict__ W1,
                                               const float* __restrict__ b1,
                                               const float* __restrict__ W2,
                                               const float* __restrict__ b2,
                                               float* __restrict__ meta) {
    __shared__ float qs[EE];            // query row, 4 KB
    __shared__ float w1s[128 * HH];     // one e-tile of W1, 52.2 KB
    __shared__ float hidp[2 * HH];      // partial hidden sums (two e-halves)
    __shared__ float hid[HH];           // combined relu(hidden)

    const int b   = blockIdx.x;
    const int tid = threadIdx.x;
    const int p   = tid >> 7;       // which e-half this thread accumulates (0/1)
    const int hh  = tid & 127;      // hidden index within half-block

    // load query row (coalesced float4)
    const float4* q4 = (const float4*)(query + (size_t)b * EE);
    for (int i = tid; i < EE / 4; i += 256) ((float4*)qs)[i] = q4[i];

    float acc = 0.f;
    // 8 e-tiles of 128; even tiles -> half 0, odd tiles -> half 1
    for (int et = 0; et < EE / 128; ++et) {
        __syncthreads();
        const float4* src = (const float4*)(W1 + (size_t)et * 128 * HH);
        for (int i = tid; i < 128 * HH / 4; i += 256) ((float4*)w1s)[i] = src[i];
        __syncthreads();
        if (hh < HH && (et & 1) == p) {
            const int e0 = et * 128;
            #pragma unroll 8
            for (int e = 0; e < 128; ++e)
                acc = fmaf(qs[e0 + e], w1s[e * HH + hh], acc);
        }
    }
    if (hh < HH) hidp[p * HH + hh] = acc;
    __syncthreads();
    if (tid < HH) hid[tid] = fmaxf(hidp[tid] + hidp[HH + tid] + b1[tid], 0.f);
    __syncthreads();

    if (tid < 64) {  // wave 0 finishes: gbk, sig/mu, window, alpha
        float p0 = 0.f, p1 = 0.f;
        for (int h = tid; h < HH; h += 64) {
            const float hv = hid[h];
            p0 = fmaf(hv, W2[2 * h + 0], p0);
            p1 = fmaf(hv, W2[2 * h + 1], p1);
        }
        for (int m = 32; m >= 1; m >>= 1) {
            p0 += __shfl_xor(p0, m, 64);
            p1 += __shfl_xor(p1, m, 64);
        }
        const float g0  = p0 + b2[0];            // b_t
        const float g1  = p1 + b2[1];            // k_t
        const float sig = sigmoidf_(g0) * 0.5f + 0.5f;   // in (0.5, 1]
        const float mu  = mu_tm1[b] + sigmoidf_(g1);

        // window: 0.5*sig*w^2 >= 45  =>  truncated phi <= e^-45 ~ 3e-20
        const float w = ceilf(sqrtf(90.0f / sig));       // <= 14
        int j0 = max(0, (int)ceilf(mu - w));
        j0 = min(j0, TT - 1);
        int j1 = min(TT - 1, (int)floorf(mu + w));
        int n  = max(1, min(j1 - j0 + 1, 61));           // structurally <= 29

        float ph = 0.f;
        if (tid < n) {
            const float dd = mu - (float)(j0 + tid);
            ph = expf(-0.5f * sig * dd * dd);
        }
        float sp = ph;
        for (int m = 32; m >= 1; m >>= 1) sp += __shfl_xor(sp, m, 64);
        // exact tail of the denominator: T * 1e-8
        const float Z = COEF * sp + (float)TT * 1e-8f;

        float* mb = meta + b * 64;
        if (tid == 0) { mb[0] = (float)j0; mb[1] = (float)n; }
        if (tid < 62) mb[2 + tid] = (tid < n) ? (COEF * ph + 1e-8f) / Z : 0.f;
    }
}

// Kernel B: c[b][d] = sum_k alpha[k] * x[b][j0+k][d]
__global__ __launch_bounds__(128) void k_ctx(const float* __restrict__ x,
                                             const float* __restrict__ meta,
                                             float* __restrict__ out) {
    __shared__ float al[64];
    const int b = blockIdx.x;
    const int d = blockIdx.y * 128 + threadIdx.x;
    if (threadIdx.x < 64) al[threadIdx.x] = meta[b * 64 + threadIdx.x];
    __syncthreads();
    const int j0 = (int)al[0];
    const int n  = (int)al[1];
    const float* xb = x + ((size_t)b * TT + (size_t)j0) * DD + d;
    float acc = 0.f;
    for (int k = 0; k < n; ++k)
        acc = fmaf(al[2 + k], xb[(size_t)k * DD], acc);
    out[(size_t)b * DD + d] = acc;
}

extern "C" void kernel_launch(void* const* d_in, const int* in_sizes, int n_in,
                              void* d_out, int out_size, void* d_ws, size_t ws_size,
                              hipStream_t stream) {
    const float* query  = (const float*)d_in[0];
    const float* x      = (const float*)d_in[1];
    const float* mu_tm1 = (const float*)d_in[2];
    const float* W1     = (const float*)d_in[3];
    const float* b1     = (const float*)d_in[4];
    const float* W2     = (const float*)d_in[5];
    const float* b2     = (const float*)d_in[6];
    float* out  = (float*)d_out;
    float* meta = (float*)d_ws;   // 64 batches * 64 floats = 16 KB

    hipLaunchKernelGGL(k_alpha, dim3(BB), dim3(256), 0, stream,
                       query, mu_tm1, W1, b1, W2, b2, meta);
    hipLaunchKernelGGL(k_ctx, dim3(BB, DD / 128), dim3(128), 0, stream,
                       x, meta, out);
}

// Round 2
// 15.638 us; speedup vs baseline: 2.0348x; 2.0348x over previous
//
#include <hip/hip_runtime.h>
#include <cmath>

#define BB 64
#define TT 2048
#define DD 512
#define EE 1024
#define HH 102
#define COEF 0.3989422917366028f

__device__ __forceinline__ float sigmoidf_(float x) { return 1.0f / (1.0f + expf(-x)); }

// One fused kernel: per-batch MLP -> sig/mu -> windowed alpha (LDS) -> context.
// grid = 64 (one block per batch), block = 256.
__global__ __launch_bounds__(256) void k_fused(const float* __restrict__ query,
                                               const float* __restrict__ x,
                                               const float* __restrict__ mu_tm1,
                                               const float* __restrict__ W1,
                                               const float* __restrict__ b1,
                                               const float* __restrict__ W2,
                                               const float* __restrict__ b2,
                                               float* __restrict__ out) {
    __shared__ float qs[EE];          // query row, 4 KB
    __shared__ float hidp[4][HH];     // per-quarter partial hidden sums
    __shared__ float hid[HH];         // relu(hidden)
    __shared__ float al[64];          // [0]=j0, [1]=n, [2..]=alpha

    const int b   = blockIdx.x;
    const int tid = threadIdx.x;

    // ---- load query row (coalesced float4) ----
    const float4* q4 = (const float4*)(query + (size_t)b * EE);
    for (int i = tid; i < EE / 4; i += 256) ((float4*)qs)[i] = q4[i];
    __syncthreads();

    // ---- MLP layer 1: hid[h] = relu(sum_e q[e]*W1[e][h] + b1[h]) ----
    // Thread layout: quarter q = tid>>6 owns e in [q*256,(q+1)*256);
    // hp = tid&63 owns hidden pair (2*hp, 2*hp+1), active for hp<51.
    {
        const int qq = tid >> 6;
        const int hp = tid & 63;
        if (hp < 51) {
            const float* qp = qs + qq * 256;
            const float* wbase = W1 + (size_t)qq * 256 * HH + 2 * hp;
            float a0 = 0.f, a1 = 0.f, a2 = 0.f, a3 = 0.f;
            #pragma unroll 8
            for (int e = 0; e < 256; e += 2) {
                const float2 w0 = *(const float2*)(wbase + (size_t)e * HH);
                const float2 w1 = *(const float2*)(wbase + (size_t)(e + 1) * HH);
                a0 = fmaf(qp[e],     w0.x, a0);
                a1 = fmaf(qp[e],     w0.y, a1);
                a2 = fmaf(qp[e + 1], w1.x, a2);
                a3 = fmaf(qp[e + 1], w1.y, a3);
            }
            hidp[qq][2 * hp]     = a0 + a2;
            hidp[qq][2 * hp + 1] = a1 + a3;
        }
    }
    __syncthreads();
    if (tid < HH)
        hid[tid] = fmaxf(hidp[0][tid] + hidp[1][tid] + hidp[2][tid] + hidp[3][tid] + b1[tid], 0.f);
    __syncthreads();

    // ---- layer 2 + window + alpha (wave 0 only) ----
    if (tid < 64) {
        float p0 = 0.f, p1 = 0.f;
        for (int h = tid; h < HH; h += 64) {
            const float hv = hid[h];
            p0 = fmaf(hv, W2[2 * h + 0], p0);
            p1 = fmaf(hv, W2[2 * h + 1], p1);
        }
        for (int m = 32; m >= 1; m >>= 1) {
            p0 += __shfl_xor(p0, m, 64);
            p1 += __shfl_xor(p1, m, 64);
        }
        const float sig = sigmoidf_(p0 + b2[0]) * 0.5f + 0.5f;   // in (0.5, 1]
        const float mu  = mu_tm1[b] + sigmoidf_(p1 + b2[1]);

        // window: 0.5*sig*w^2 >= 45 => truncated phi <= e^-45
        const float w = ceilf(sqrtf(90.0f / sig));               // <= 14
        int j0 = max(0, (int)ceilf(mu - w));
        j0 = min(j0, TT - 1);
        const int j1 = min(TT - 1, (int)floorf(mu + w));
        const int n  = max(1, min(j1 - j0 + 1, 61));             // structurally <= 29

        float ph = 0.f;
        if (tid < n) {
            const float dd = mu - (float)(j0 + tid);
            ph = expf(-0.5f * sig * dd * dd);
        }
        float sp = ph;
        for (int m = 32; m >= 1; m >>= 1) sp += __shfl_xor(sp, m, 64);
        const float Z = COEF * sp + (float)TT * 1e-8f;           // exact 1e-8 tail in denom

        if (tid == 0) { al[0] = (float)j0; al[1] = (float)n; }
        if (tid < 62) al[2 + tid] = (tid < n) ? (COEF * ph + 1e-8f) / Z : 0.f;
    }
    __syncthreads();

    // ---- context: c[b][d] = sum_k alpha[k] * x[b][j0+k][d] ----
    const int j0 = (int)al[0];
    const int n  = (int)al[1];
    const float* xb = x + ((size_t)b * TT + (size_t)j0) * DD;
    float c0 = 0.f, c1 = 0.f;
    for (int k = 0; k < n; ++k) {
        const float a = al[2 + k];
        c0 = fmaf(a, xb[(size_t)k * DD + tid],       c0);
        c1 = fmaf(a, xb[(size_t)k * DD + tid + 256], c1);
    }
    out[(size_t)b * DD + tid]       = c0;
    out[(size_t)b * DD + tid + 256] = c1;
}

extern "C" void kernel_launch(void* const* d_in, const int* in_sizes, int n_in,
                              void* d_out, int out_size, void* d_ws, size_t ws_size,
                              hipStream_t stream) {
    const float* query  = (const float*)d_in[0];
    const float* x      = (const float*)d_in[1];
    const float* mu_tm1 = (const float*)d_in[2];
    const float* W1     = (const float*)d_in[3];
    const float* b1     = (const float*)d_in[4];
    const float* W2     = (const float*)d_in[5];
    const float* b2     = (const float*)d_in[6];
    float* out = (float*)d_out;

    hipLaunchKernelGGL(k_fused, dim3(BB), dim3(256), 0, stream,
                       query, x, mu_tm1, W1, b1, W2, b2, out);
}

// Round 3
// 15.614 us; speedup vs baseline: 2.0380x; 1.0016x over previous
//
#include <hip/hip_runtime.h>
#include <cmath>

#define BB 64
#define TT 2048
#define DD 512
#define EE 1024
#define HH 102
#define MAXW 29              // sig > 0.5 => half-width <= 14 => window <= 29 rows
#define COEF 0.3989422917366028f

__device__ __forceinline__ float sigmoidf_(float x) { return 1.0f / (1.0f + expf(-x)); }

// One fused kernel, one block per batch, 1024 threads.
// Phases: q->LDS | layer1 (16-way e-split) | layer2+alpha (wave0) |
//         window->LDS (all threads, float4) | ctx reduce (512 threads).
__global__ __launch_bounds__(1024) void k_fused(const float* __restrict__ query,
                                                const float* __restrict__ x,
                                                const float* __restrict__ mu_tm1,
                                                const float* __restrict__ W1,
                                                const float* __restrict__ b1,
                                                const float* __restrict__ W2,
                                                const float* __restrict__ b2,
                                                float* __restrict__ out) {
    __shared__ float4 xw4[MAXW * (DD / 4)];   // 59.4 KB window
    __shared__ float  qs[EE];                 // 4 KB
    __shared__ float  hidp[16][HH];           // 6.5 KB partial hidden
    __shared__ float  hid[HH];
    __shared__ float  al[32];                 // [0]=j0, [1]=n, [2..30]=alpha
    float* xw = (float*)xw4;

    const int b   = blockIdx.x;
    const int tid = threadIdx.x;

    // ---- query row -> LDS ----
    if (tid < EE / 4) ((float4*)qs)[tid] = ((const float4*)(query + (size_t)b * EE))[tid];
    __syncthreads();

    // ---- layer 1: 16 e-slices x 51 hidden-pairs ----
    {
        const int sl = tid >> 6;          // e-slice 0..15 (64 e each)
        const int hp = tid & 63;          // hidden pair, active < 51
        if (hp < 51) {
            const float* qp = qs + sl * 64;
            const float* wbase = W1 + (size_t)sl * 64 * HH + 2 * hp;
            float a0 = 0.f, a1 = 0.f, a2 = 0.f, a3 = 0.f;
            #pragma unroll 8
            for (int e = 0; e < 64; e += 2) {
                const float2 w0 = *(const float2*)(wbase + (size_t)e * HH);
                const float2 w1 = *(const float2*)(wbase + (size_t)(e + 1) * HH);
                a0 = fmaf(qp[e],     w0.x, a0);
                a1 = fmaf(qp[e],     w0.y, a1);
                a2 = fmaf(qp[e + 1], w1.x, a2);
                a3 = fmaf(qp[e + 1], w1.y, a3);
            }
            hidp[sl][2 * hp]     = a0 + a2;
            hidp[sl][2 * hp + 1] = a1 + a3;
        }
    }
    __syncthreads();
    if (tid < HH) {
        float s = b1[tid];
        #pragma unroll
        for (int sl = 0; sl < 16; ++sl) s += hidp[sl][tid];
        hid[tid] = fmaxf(s, 0.f);
    }
    __syncthreads();

    // ---- layer 2 + window + alpha (wave 0) ----
    if (tid < 64) {
        float p0 = 0.f, p1 = 0.f;
        for (int h = tid; h < HH; h += 64) {
            const float hv = hid[h];
            p0 = fmaf(hv, W2[2 * h + 0], p0);
            p1 = fmaf(hv, W2[2 * h + 1], p1);
        }
        for (int m = 32; m >= 1; m >>= 1) {
            p0 += __shfl_xor(p0, m, 64);
            p1 += __shfl_xor(p1, m, 64);
        }
        const float sig = sigmoidf_(p0 + b2[0]) * 0.5f + 0.5f;   // (0.5, 1]
        const float mu  = mu_tm1[b] + sigmoidf_(p1 + b2[1]);

        const float w = ceilf(sqrtf(90.0f / sig));               // <= 14
        int j0 = max(0, (int)ceilf(mu - w));
        j0 = min(j0, TT - 1);
        const int j1 = min(TT - 1, (int)floorf(mu + w));
        const int n  = max(1, min(j1 - j0 + 1, MAXW));

        float ph = 0.f;
        if (tid < n) {
            const float dd = mu - (float)(j0 + tid);
            ph = expf(-0.5f * sig * dd * dd);
        }
        float sp = ph;
        for (int m = 32; m >= 1; m >>= 1) sp += __shfl_xor(sp, m, 64);
        const float Z = COEF * sp + (float)TT * 1e-8f;           // exact 1e-8 tail

        if (tid == 0) { al[0] = (float)j0; al[1] = (float)n; }
        if (tid < MAXW) al[2 + tid] = (tid < n) ? (COEF * ph + 1e-8f) / Z : 0.f;
    }
    __syncthreads();

    // ---- cooperative window load: 8 rows per iteration (1024 x float4) ----
    const int j0 = (int)al[0];
    const int n  = (int)al[1];
    {
        const int r = tid >> 7;           // row within group of 8
        const int c = tid & 127;          // float4 column
        const float4* xb4 = (const float4*)(x + ((size_t)b * TT + (size_t)j0) * DD);
        #pragma unroll
        for (int k8 = 0; k8 < (MAXW + 7) / 8; ++k8) {
            const int k = k8 * 8 + r;
            if (k < n) xw4[k * (DD / 4) + c] = xb4[(size_t)k * (DD / 4) + c];
        }
    }
    __syncthreads();

    // ---- ctx reduce: thread d sums over k ----
    if (tid < DD) {
        float acc = 0.f;
        for (int k = 0; k < n; ++k)
            acc = fmaf(al[2 + k], xw[k * DD + tid], acc);
        out[(size_t)b * DD + tid] = acc;
    }
}

extern "C" void kernel_launch(void* const* d_in, const int* in_sizes, int n_in,
                              void* d_out, int out_size, void* d_ws, size_t ws_size,
                              hipStream_t stream) {
    const float* query  = (const float*)d_in[0];
    const float* x      = (const float*)d_in[1];
    const float* mu_tm1 = (const float*)d_in[2];
    const float* W1     = (const float*)d_in[3];
    const float* b1     = (const float*)d_in[4];
    const float* W2     = (const float*)d_in[5];
    const float* b2     = (const float*)d_in[6];
    float* out = (float*)d_out;

    hipLaunchKernelGGL(k_fused, dim3(BB), dim3(1024), 0, stream,
                       query, x, mu_tm1, W1, b1, W2, b2, out);
}